// Round 5
// baseline (206.789 us; speedup 1.0000x reference)
//
#include <hip/hip_runtime.h>

#define SEQ_LEN 16384
#define ENC_H   2048
#define DEC_H   2048
#define NB_SC   1024                 // k_scores blocks: 16 rows each, 4 rows per wave
#define NB_CTX  1024                 // k_ctx blocks: 16-row chunks
#define CHUNK   (SEQ_LEN / NB_CTX)   // 16
#define WTHR    1e-9f                // skip threshold; err <= 16384*1e-9*max|enc| ~ 1e-4

// ---------------- K1: v[b] = W[b,:] . dec ; one block per row ----------------
__global__ __launch_bounds__(256) void k_wv(const float* __restrict__ W,
                                            const float* __restrict__ dec,
                                            float* __restrict__ v,
                                            float* __restrict__ out) {
    __shared__ float sred[4];
    const int b = blockIdx.x, t = threadIdx.x, lane = t & 63, wave = t >> 6;
    if (b < ENC_H / 256) out[b * 256 + t] = 0.f;           // zero d_out
    const float4* Wr = (const float4*)(W + (size_t)b * DEC_H);
    const float4* d4 = (const float4*)dec;
    const float4 a0 = Wr[t], a1 = Wr[t + 256];
    const float4 d0 = d4[t], d1 = d4[t + 256];
    float acc = a0.x * d0.x + a0.y * d0.y + a0.z * d0.z + a0.w * d0.w
              + a1.x * d1.x + a1.y * d1.y + a1.z * d1.z + a1.w * d1.w;
#pragma unroll
    for (int off = 32; off > 0; off >>= 1) acc += __shfl_down(acc, off, 64);
    if (lane == 0) sred[wave] = acc;
    __syncthreads();
    if (t == 0) v[b] = sred[0] + sred[1] + sred[2] + sred[3];
}

// ------- K2: scores + block softmax state; v in REGISTERS, pure-global K-loop -------
__global__ __launch_bounds__(256) void k_scores(const float* __restrict__ enc,
                                                const float* __restrict__ v,
                                                float* __restrict__ scores,
                                                float* __restrict__ bmax,
                                                float* __restrict__ bsum) {
    __shared__ float4 sv[ENC_H / 4];   // 8 KB, prologue-only
    __shared__ float smax[4], ssum[4];
    const int t = threadIdx.x, lane = t & 63, wave = t >> 6;
    const float4* v4 = (const float4*)v;
    for (int i = t; i < ENC_H / 4; i += 256) sv[i] = v4[i];
    __syncthreads();
    float4 vr[8];                      // lane's v slice: 32 VGPRs, loop-invariant
#pragma unroll
    for (int k = 0; k < 8; ++k) vr[k] = sv[k * 64 + lane];

    const int r0 = blockIdx.x * 16 + wave * 4;             // 4 rows per wave
    const float4* e0 = (const float4*)(enc + (size_t)(r0 + 0) * ENC_H);
    const float4* e1 = (const float4*)(enc + (size_t)(r0 + 1) * ENC_H);
    const float4* e2 = (const float4*)(enc + (size_t)(r0 + 2) * ENC_H);
    const float4* e3 = (const float4*)(enc + (size_t)(r0 + 3) * ENC_H);
    float a0 = 0.f, a1 = 0.f, a2 = 0.f, a3 = 0.f;
#pragma unroll
    for (int k = 0; k < 8; ++k) {      // body: 4 indep global loads + FMAs, no LDS
        const int i = k * 64 + lane;
        const float4 w = vr[k];
        const float4 x0 = e0[i], x1 = e1[i], x2 = e2[i], x3 = e3[i];
        a0 += x0.x * w.x + x0.y * w.y + x0.z * w.z + x0.w * w.w;
        a1 += x1.x * w.x + x1.y * w.y + x1.z * w.z + x1.w * w.w;
        a2 += x2.x * w.x + x2.y * w.y + x2.z * w.z + x2.w * w.w;
        a3 += x3.x * w.x + x3.y * w.y + x3.z * w.z + x3.w * w.w;
    }
#pragma unroll
    for (int off = 32; off > 0; off >>= 1) {
        a0 += __shfl_down(a0, off, 64);
        a1 += __shfl_down(a1, off, 64);
        a2 += __shfl_down(a2, off, 64);
        a3 += __shfl_down(a3, off, 64);
    }
    if (lane == 0) {
        scores[r0 + 0] = a0; scores[r0 + 1] = a1;
        scores[r0 + 2] = a2; scores[r0 + 3] = a3;
        const float m = fmaxf(fmaxf(a0, a1), fmaxf(a2, a3));
        smax[wave] = m;
        ssum[wave] = __expf(a0 - m) + __expf(a1 - m) + __expf(a2 - m) + __expf(a3 - m);
    }
    __syncthreads();
    if (t == 0) {
        const float bm = fmaxf(fmaxf(smax[0], smax[1]), fmaxf(smax[2], smax[3]));
        float bs = 0.f;
#pragma unroll
        for (int w2 = 0; w2 < 4; ++w2) bs += ssum[w2] * __expf(smax[w2] - bm);
        bmax[blockIdx.x] = bm; bsum[blockIdx.x] = bs;
    }
}

// ------- K3: softmax finalize + sparse context; 16-row chunks, skip tiny -------
__global__ __launch_bounds__(256) void k_ctx(const float* __restrict__ enc,
                                             const float* __restrict__ scores,
                                             const float* __restrict__ bmax,
                                             const float* __restrict__ bsum,
                                             float* __restrict__ out) {
    __shared__ float sred[4], sw[CHUNK];
    const int t = threadIdx.x, lane = t & 63, wave = t >> 6;

    float m = fmaxf(fmaxf(bmax[t], bmax[t + 256]), fmaxf(bmax[t + 512], bmax[t + 768]));
#pragma unroll
    for (int off = 32; off > 0; off >>= 1) m = fmaxf(m, __shfl_down(m, off, 64));
    if (lane == 0) sred[wave] = m;
    __syncthreads();
    m = fmaxf(fmaxf(sred[0], sred[1]), fmaxf(sred[2], sred[3]));
    __syncthreads();
    float s = bsum[t]       * __expf(bmax[t]       - m)
            + bsum[t + 256] * __expf(bmax[t + 256] - m)
            + bsum[t + 512] * __expf(bmax[t + 512] - m)
            + bsum[t + 768] * __expf(bmax[t + 768] - m);
#pragma unroll
    for (int off = 32; off > 0; off >>= 1) s += __shfl_down(s, off, 64);
    if (lane == 0) sred[wave] = s;
    __syncthreads();
    const float inv = 1.f / (sred[0] + sred[1] + sred[2] + sred[3]);

    const int b = blockIdx.x;
    if (t < CHUNK) sw[t] = __expf(scores[b * CHUNK + t] - m) * inv;
    __syncthreads();
    float wmax = 0.f;
#pragma unroll
    for (int r = 0; r < CHUNK; ++r) wmax = fmaxf(wmax, sw[r]);
    if (wmax <= WTHR) return;              // uniform exit; skipped mass < 1.6e-5

    const float4* e4 = (const float4*)enc;
    float4 c0 = {0.f, 0.f, 0.f, 0.f}, c1 = {0.f, 0.f, 0.f, 0.f};
    const size_t base = (size_t)b * CHUNK * (ENC_H / 4);
#pragma unroll
    for (int rb = 0; rb < CHUNK / 4; ++rb) {
        const size_t r0 = base + (size_t)(rb * 4) * (ENC_H / 4);
        const float w0 = sw[rb * 4 + 0], w1 = sw[rb * 4 + 1];
        const float w2 = sw[rb * 4 + 2], w3 = sw[rb * 4 + 3];
        const float4 x0 = e4[r0 + t],               y0 = e4[r0 + t + 256];
        const float4 x1 = e4[r0 + (ENC_H/4) + t],   y1 = e4[r0 + (ENC_H/4) + t + 256];
        const float4 x2 = e4[r0 + 2*(ENC_H/4) + t], y2 = e4[r0 + 2*(ENC_H/4) + t + 256];
        const float4 x3 = e4[r0 + 3*(ENC_H/4) + t], y3 = e4[r0 + 3*(ENC_H/4) + t + 256];
        c0.x += w0*x0.x + w1*x1.x + w2*x2.x + w3*x3.x;
        c0.y += w0*x0.y + w1*x1.y + w2*x2.y + w3*x3.y;
        c0.z += w0*x0.z + w1*x1.z + w2*x2.z + w3*x3.z;
        c0.w += w0*x0.w + w1*x1.w + w2*x2.w + w3*x3.w;
        c1.x += w0*y0.x + w1*y1.x + w2*y2.x + w3*y3.x;
        c1.y += w0*y0.y + w1*y1.y + w2*y2.y + w3*y3.y;
        c1.z += w0*y0.z + w1*y1.z + w2*y2.z + w3*y3.z;
        c1.w += w0*y0.w + w1*y1.w + w2*y2.w + w3*y3.w;
    }
    atomicAdd(&out[4 * t + 0], c0.x);
    atomicAdd(&out[4 * t + 1], c0.y);
    atomicAdd(&out[4 * t + 2], c0.z);
    atomicAdd(&out[4 * t + 3], c0.w);
    atomicAdd(&out[4 * (t + 256) + 0], c1.x);
    atomicAdd(&out[4 * (t + 256) + 1], c1.y);
    atomicAdd(&out[4 * (t + 256) + 2], c1.z);
    atomicAdd(&out[4 * (t + 256) + 3], c1.w);
}

extern "C" void kernel_launch(void* const* d_in, const int* in_sizes, int n_in,
                              void* d_out, int out_size, void* d_ws, size_t ws_size,
                              hipStream_t stream) {
    const float* enc = (const float*)d_in[0];   // [16384, 2048]
    const float* dec = (const float*)d_in[1];   // [1, 2048]
    const float* W   = (const float*)d_in[2];   // [2048, 2048]
    float* out = (float*)d_out;                 // [1, 2048]

    float* ws     = (float*)d_ws;
    float* v      = ws;                  // 2048
    float* scores = v + ENC_H;           // 16384
    float* bmax   = scores + SEQ_LEN;    // 1024
    float* bsum   = bmax + NB_SC;        // 1024

    k_wv    <<<ENC_H,  256, 0, stream>>>(W, dec, v, out);
    k_scores<<<NB_SC,  256, 0, stream>>>(enc, v, scores, bmax, bsum);
    k_ctx   <<<NB_CTX, 256, 0, stream>>>(enc, scores, bmax, bsum, out);
}